// Round 4
// baseline (158.549 us; speedup 1.0000x reference)
//
#include <hip/hip_runtime.h>

// Problem constants (from the reference):
//   B=32768 batch, T=256 trees, D=10 depth, F=512 features, C=1 leaf dim
constexpr int kB = 32768;
constexpr int kT = 256;
constexpr int kD = 10;
constexpr int kF = 512;
constexpr int kLvlPad = kT << (kD - 1); // 131072
constexpr int kLevels = kD - 1;         // 9

constexpr int kRows    = 16;            // batch rows per block
constexpr int kTrees   = 32;            // trees per block (256/32 = 8 tiles = 8 XCDs)
constexpr int kThreads = kRows * kTrees; // 512
constexpr int kXPad    = 516;           // padded x row stride (floats)
constexpr int kShallow = 5;             // levels 1..5 staged in LDS
constexpr int kTblEntries = kTrees * ((2 << kShallow) - 2); // 32*62 = 1984

// Native vector type usable with __builtin_nontemporal_load.
typedef float vfloat4 __attribute__((ext_vector_type(4)));

// Prep: interleave (node, bias) -> one 8B gather per level instead of two 4B.
__global__ __launch_bounds__(256)
void pack_kernel(const int* __restrict__ nodes, const float* __restrict__ biases,
                 int2* __restrict__ packed, int n)
{
    int i = blockIdx.x * 256 + threadIdx.x;
    if (i < n)
        packed[i] = make_int2(nodes[i], __float_as_int(biases[i]));
}

// Block = 16 batch rows x 32 trees. 1D grid; blockIdx&7 selects the tree tile
// so each XCD (round-robin block->XCD) only touches its own 32 trees' tables
// (~390 KB incl. leaves -> L2-resident). Wave lanes: lane&15 = row -> 16 lanes
// share a tree, so level-i gathers coalesce within the tree's 2^i window.
// Levels 1..5 are staged in LDS; x rows staged in LDS (non-temporal loads).
template<bool PACKED>
__global__ __launch_bounds__(kThreads)
void traverse_kernel(const float* __restrict__ x,
                     const int* __restrict__ root_nodes,
                     const float* __restrict__ root_biases,
                     const int* __restrict__ nodes,
                     const float* __restrict__ biases,
                     const int2* __restrict__ packed,
                     const float* __restrict__ leaf_nodes,
                     float* __restrict__ out)
{
    __shared__ float xs[kRows][kXPad];      // 33,024 B
    __shared__ int2  tbl[kTblEntries];      // 15,872 B
    __shared__ float outs[kRows][kTrees];   //  2,048 B

    const int bid   = blockIdx.x;
    const int ttile = bid & 7;        // tree tile -> XCD (round-robin heuristic)
    const int btile = bid >> 3;
    const int b0    = btile * kRows;
    const int t0    = ttile * kTrees;
    const int tid   = threadIdx.x;

    // Stage 16 x rows (2048 float4), coalesced, non-temporal (streamed once).
    {
        const vfloat4* xg = reinterpret_cast<const vfloat4*>(x + (size_t)b0 * kF);
#pragma unroll
        for (int k = 0; k < 4; ++k) {
            int j = tid + k * kThreads;   // 0..2047
            int r = j >> 7;
            int c = j & 127;
            vfloat4 v = __builtin_nontemporal_load(&xg[(size_t)r * (kF / 4) + c]);
            *reinterpret_cast<vfloat4*>(&xs[r][c * 4]) = v;
        }
    }
    // Stage levels 1..5 for this block's 32 trees into LDS.
    for (int j = tid; j < kTblEntries; j += kThreads) {
        int i, base;
        if      (j <  64) { i = 1; base =   0; }
        else if (j < 192) { i = 2; base =  64; }
        else if (j < 448) { i = 3; base = 192; }
        else if (j < 960) { i = 4; base = 448; }
        else              { i = 5; base = 960; }
        int local = j - base;             // = tt*2^i + w
        size_t g = (size_t)(i - 1) * kLvlPad + ((size_t)t0 << i) + local;
        tbl[j] = make_int2(nodes[g], __float_as_int(biases[g]));
    }
    __syncthreads();

    const int r  = tid & (kRows - 1);
    const int tt = tid >> 4;
    const int t  = t0 + tt;
    const float* __restrict__ xrow = xs[r];

    // Root (t uniform across 16 lanes -> broadcast loads, tables tiny/L2-hot).
    int prev = 2 * t + (xrow[root_nodes[t]] <= root_biases[t] ? 1 : 0);

    // Shallow levels from LDS.
    constexpr int bases[6] = {0, 0, 64, 192, 448, 960};
#pragma unroll
    for (int i = 1; i <= kShallow; ++i) {
        int2 nb = tbl[bases[i] + (prev - (t0 << i))];
        prev = 2 * prev + (xrow[nb.x] <= __int_as_float(nb.y) ? 1 : 0);
    }
    // Deep levels from global (per-XCD slice is L2-resident).
#pragma unroll
    for (int i = kShallow + 1; i < kD; ++i) {
        int node; float bias;
        if (PACKED) {
            int2 nb = packed[(size_t)(i - 1) * kLvlPad + prev];
            node = nb.x;
            bias = __int_as_float(nb.y);
        } else {
            node = nodes [(size_t)(i - 1) * kLvlPad + prev];
            bias = biases[(size_t)(i - 1) * kLvlPad + prev];
        }
        prev = 2 * prev + (xrow[node] <= bias ? 1 : 0);
    }

    // Leaf gather (C == 1), then coalesced non-temporal store via LDS.
    outs[r][tt] = leaf_nodes[prev];
    __syncthreads();
    {
        int orow = tid >> 5;
        int ocol = tid & 31;
        __builtin_nontemporal_store(outs[orow][ocol],
                                    &out[(size_t)(b0 + orow) * kT + t0 + ocol]);
    }
}

extern "C" void kernel_launch(void* const* d_in, const int* in_sizes, int n_in,
                              void* d_out, int out_size, void* d_ws, size_t ws_size,
                              hipStream_t stream) {
    const float* x           = (const float*)d_in[0];
    const int*   root_nodes  = (const int*)d_in[1];
    const float* root_biases = (const float*)d_in[2];
    const int*   nodes       = (const int*)d_in[3];
    const float* biases      = (const float*)d_in[4];
    const float* leaf_nodes  = (const float*)d_in[5];
    float*       out         = (float*)d_out;

    const size_t packed_bytes = (size_t)kLevels * kLvlPad * sizeof(int2); // 9.44 MB
    const int nblocks = (kB / kRows) * (kT / kTrees); // 2048 * 8 = 16384

    if (ws_size >= packed_bytes) {
        const int n = kLevels * kLvlPad;
        pack_kernel<<<(n + 255) / 256, 256, 0, stream>>>(nodes, biases, (int2*)d_ws, n);
        traverse_kernel<true><<<nblocks, kThreads, 0, stream>>>(
            x, root_nodes, root_biases, nodes, biases,
            (const int2*)d_ws, leaf_nodes, out);
    } else {
        traverse_kernel<false><<<nblocks, kThreads, 0, stream>>>(
            x, root_nodes, root_biases, nodes, biases,
            nullptr, leaf_nodes, out);
    }
}

// Round 5
// 110.208 us; speedup vs baseline: 1.4386x; 1.4386x over previous
//
#include <hip/hip_runtime.h>

// Problem constants (from the reference):
//   B=32768 batch, T=256 trees, D=10 depth, F=512 features, C=1 leaf dim
constexpr int kB = 32768;
constexpr int kT = 256;
constexpr int kD = 10;
constexpr int kF = 512;
constexpr int kLvlPad = kT << (kD - 1); // 131072
constexpr int kLevels = kD - 1;         // 9

constexpr int kRows    = 16;             // batch rows per block
constexpr int kTrees   = 64;             // trees per block (2 per thread)
constexpr int kThreads = 512;
constexpr int kXPad    = 516;            // padded x row stride (floats)

// Prep: interleave (node, bias) -> one 8B gather per level instead of two 4B.
__global__ __launch_bounds__(256)
void pack_kernel(const int* __restrict__ nodes, const float* __restrict__ biases,
                 int2* __restrict__ packed, int n)
{
    int i = blockIdx.x * 256 + threadIdx.x;
    if (i < n)
        packed[i] = make_int2(nodes[i], __float_as_int(biases[i]));
}

// Block = 16 batch rows x 64 trees, 512 threads, 2 independent (row,tree)
// chains per thread (trees tt and tt+32) for 2x memory-level parallelism in
// the latency-bound dependent-gather walk. Wave lanes: lane&15 = row ->
// 16 lanes share each tree, so level-i gathers coalesce within the tree's
// 2^i-entry window. x rows staged in LDS; outputs staged for coalesced NT
// stores.
template<bool PACKED>
__global__ __launch_bounds__(kThreads)
void traverse_kernel(const float* __restrict__ x,
                     const int* __restrict__ root_nodes,
                     const float* __restrict__ root_biases,
                     const int* __restrict__ nodes,
                     const float* __restrict__ biases,
                     const int2* __restrict__ packed,
                     const float* __restrict__ leaf_nodes,
                     float* __restrict__ out)
{
    __shared__ float xs[kRows][kXPad];       // 33,024 B
    __shared__ float outs[kRows][kTrees];    //  4,096 B

    const int b0  = blockIdx.x * kRows;
    const int t0  = blockIdx.y * kTrees;
    const int tid = threadIdx.x;

    // Stage 16 x rows (2048 float4), coalesced.
    {
        const float4* xg = reinterpret_cast<const float4*>(x + (size_t)b0 * kF);
#pragma unroll
        for (int k = 0; k < 4; ++k) {
            int j = tid + k * kThreads;   // 0..2047
            int r = j >> 7;
            int c = j & 127;
            float4 v = xg[(size_t)r * (kF / 4) + c];
            *reinterpret_cast<float4*>(&xs[r][c * 4]) = v;
        }
    }
    __syncthreads();

    const int r  = tid & (kRows - 1); // row within tile
    const int tt = tid >> 4;          // 0..31
    const int tA = t0 + tt;
    const int tB = t0 + tt + 32;
    const float* __restrict__ xrow = xs[r];

    // Root level (tree uniform across each 16-lane group -> broadcast loads).
    int pA = 2 * tA + (xrow[root_nodes[tA]] <= root_biases[tA] ? 1 : 0);
    int pB = 2 * tB + (xrow[root_nodes[tB]] <= root_biases[tB] ? 1 : 0);

#pragma unroll
    for (int i = 1; i < kD; ++i) {
        if (PACKED) {
            const int2* lvl = packed + (size_t)(i - 1) * kLvlPad;
            int2 nbA = lvl[pA];
            int2 nbB = lvl[pB];
            pA = 2 * pA + (xrow[nbA.x] <= __int_as_float(nbA.y) ? 1 : 0);
            pB = 2 * pB + (xrow[nbB.x] <= __int_as_float(nbB.y) ? 1 : 0);
        } else {
            const int*   ln = nodes  + (size_t)(i - 1) * kLvlPad;
            const float* lb = biases + (size_t)(i - 1) * kLvlPad;
            int   nA = ln[pA], nB = ln[pB];
            float bA = lb[pA], bB = lb[pB];
            pA = 2 * pA + (xrow[nA] <= bA ? 1 : 0);
            pB = 2 * pB + (xrow[nB] <= bB ? 1 : 0);
        }
    }

    // Leaf gathers (C == 1), then coalesced non-temporal stores via LDS.
    outs[r][tt]      = leaf_nodes[pA];
    outs[r][tt + 32] = leaf_nodes[pB];
    __syncthreads();

#pragma unroll
    for (int k = 0; k < 2; ++k) {
        int j    = tid + k * kThreads;  // 0..1023
        int orow = j >> 6;              // 0..15
        int ocol = j & 63;              // 0..63
        __builtin_nontemporal_store(outs[orow][ocol],
                                    &out[(size_t)(b0 + orow) * kT + t0 + ocol]);
    }
}

extern "C" void kernel_launch(void* const* d_in, const int* in_sizes, int n_in,
                              void* d_out, int out_size, void* d_ws, size_t ws_size,
                              hipStream_t stream) {
    const float* x           = (const float*)d_in[0];
    const int*   root_nodes  = (const int*)d_in[1];
    const float* root_biases = (const float*)d_in[2];
    const int*   nodes       = (const int*)d_in[3];
    const float* biases      = (const float*)d_in[4];
    const float* leaf_nodes  = (const float*)d_in[5];
    float*       out         = (float*)d_out;

    const size_t packed_bytes = (size_t)kLevels * kLvlPad * sizeof(int2); // 9.44 MB
    dim3 grid(kB / kRows, kT / kTrees); // (2048, 4)

    if (ws_size >= packed_bytes) {
        const int n = kLevels * kLvlPad;
        pack_kernel<<<(n + 255) / 256, 256, 0, stream>>>(nodes, biases, (int2*)d_ws, n);
        traverse_kernel<true><<<grid, kThreads, 0, stream>>>(
            x, root_nodes, root_biases, nodes, biases,
            (const int2*)d_ws, leaf_nodes, out);
    } else {
        traverse_kernel<false><<<grid, kThreads, 0, stream>>>(
            x, root_nodes, root_biases, nodes, biases,
            nullptr, leaf_nodes, out);
    }
}

// Round 6
// 99.805 us; speedup vs baseline: 1.5886x; 1.1042x over previous
//
#include <hip/hip_runtime.h>

// Problem constants (from the reference):
//   B=32768 batch, T=256 trees, D=10 depth, F=512 features, C=1 leaf dim
constexpr int kB = 32768;
constexpr int kT = 256;
constexpr int kD = 10;
constexpr int kF = 512;
constexpr int kLvlPad = kT << (kD - 1); // 131072
constexpr int kLevels = kD - 1;         // 9

constexpr int kRows    = 16;             // batch rows per block
constexpr int kTrees   = 64;             // trees per block (2 per thread)
constexpr int kThreads = 512;
constexpr int kXPad    = 516;            // padded x row stride (floats)

// Prep: interleave (node, bias) -> one 8B gather per level instead of two 4B.
__global__ __launch_bounds__(256)
void pack_kernel(const int* __restrict__ nodes, const float* __restrict__ biases,
                 int2* __restrict__ packed, int n)
{
    int i = blockIdx.x * 256 + threadIdx.x;
    if (i < n)
        packed[i] = make_int2(nodes[i], __float_as_int(biases[i]));
}

// Prep: fuse iter-9 + leaf into one 16B record indexed by p8 (prev after
// iter 8, in [0, 131072)): {node9, bias9, leaf[2*p8], leaf[2*p8+1]}.
// One dwordx4 gather then finishes the tree (compare + register select).
__global__ __launch_bounds__(256)
void fuse_kernel(const int* __restrict__ nodes, const float* __restrict__ biases,
                 const float* __restrict__ leaf_nodes, int4* __restrict__ fused)
{
    int j = blockIdx.x * 256 + threadIdx.x; // 0 .. kLvlPad-1
    if (j < kLvlPad) {
        const int   n9 = nodes [(size_t)(kD - 2) * kLvlPad + j];
        const float b9 = biases[(size_t)(kD - 2) * kLvlPad + j];
        fused[j] = make_int4(n9, __float_as_int(b9),
                             __float_as_int(leaf_nodes[2 * j]),
                             __float_as_int(leaf_nodes[2 * j + 1]));
    }
}

// Block = 16 batch rows x 64 trees, 512 threads, 2 independent (row,tree)
// chains per thread for 2x memory-level parallelism. Wave lanes: lane&15 =
// row -> 16 lanes share each tree so level-i gathers coalesce in the tree's
// 2^i window. x rows staged in LDS; outputs staged for coalesced NT stores.
// TIER 2: packed rows 0..7 + fused last step. TIER 1: packed rows 0..8 +
// separate leaf gather. TIER 0: unpacked.
template<int TIER>
__global__ __launch_bounds__(kThreads)
void traverse_kernel(const float* __restrict__ x,
                     const int* __restrict__ root_nodes,
                     const float* __restrict__ root_biases,
                     const int* __restrict__ nodes,
                     const float* __restrict__ biases,
                     const int2* __restrict__ packed,
                     const int4* __restrict__ fused,
                     const float* __restrict__ leaf_nodes,
                     float* __restrict__ out)
{
    __shared__ float xs[kRows][kXPad];        // 33,024 B
    __shared__ float outs[kRows][kTrees + 1]; //  4,160 B (pad kills bank conflict)

    const int b0  = blockIdx.x * kRows;
    const int t0  = blockIdx.y * kTrees;
    const int tid = threadIdx.x;

    // Stage 16 x rows (2048 float4), coalesced.
    {
        const float4* xg = reinterpret_cast<const float4*>(x + (size_t)b0 * kF);
#pragma unroll
        for (int k = 0; k < 4; ++k) {
            int j = tid + k * kThreads;   // 0..2047
            int r = j >> 7;
            int c = j & 127;
            float4 v = xg[(size_t)r * (kF / 4) + c];
            *reinterpret_cast<float4*>(&xs[r][c * 4]) = v;
        }
    }
    __syncthreads();

    const int r  = tid & (kRows - 1); // row within tile
    const int tt = tid >> 4;          // 0..31
    const int tA = t0 + tt;
    const int tB = t0 + tt + 32;
    const float* __restrict__ xrow = xs[r];

    // Root level (tree uniform across each 16-lane group -> broadcast loads).
    int pA = 2 * tA + (xrow[root_nodes[tA]] <= root_biases[tA] ? 1 : 0);
    int pB = 2 * tB + (xrow[root_nodes[tB]] <= root_biases[tB] ? 1 : 0);

    const int last = (TIER == 2) ? kD - 1 : kD; // fused tier stops before iter 9
#pragma unroll
    for (int i = 1; i < ((TIER == 2) ? kD - 1 : kD); ++i) {
        if (TIER >= 1) {
            const int2* lvl = packed + (size_t)(i - 1) * kLvlPad;
            int2 nbA = lvl[pA];
            int2 nbB = lvl[pB];
            pA = 2 * pA + (xrow[nbA.x] <= __int_as_float(nbA.y) ? 1 : 0);
            pB = 2 * pB + (xrow[nbB.x] <= __int_as_float(nbB.y) ? 1 : 0);
        } else {
            const int*   ln = nodes  + (size_t)(i - 1) * kLvlPad;
            const float* lb = biases + (size_t)(i - 1) * kLvlPad;
            int   nA = ln[pA], nB = ln[pB];
            float bA = lb[pA], bB = lb[pB];
            pA = 2 * pA + (xrow[nA] <= bA ? 1 : 0);
            pB = 2 * pB + (xrow[nB] <= bB ? 1 : 0);
        }
    }

    if (TIER == 2) {
        // pA,pB in [0, 131072): one 16B gather finishes each tree.
        int4 fA = fused[pA];
        int4 fB = fused[pB];
        outs[r][tt] =
            __int_as_float(xrow[fA.x] <= __int_as_float(fA.y) ? fA.w : fA.z);
        outs[r][tt + 32] =
            __int_as_float(xrow[fB.x] <= __int_as_float(fB.y) ? fB.w : fB.z);
    } else {
        outs[r][tt]      = leaf_nodes[pA];
        outs[r][tt + 32] = leaf_nodes[pB];
    }
    __syncthreads();

#pragma unroll
    for (int k = 0; k < 2; ++k) {
        int j    = tid + k * kThreads;  // 0..1023
        int orow = j >> 6;              // 0..15
        int ocol = j & 63;              // 0..63
        __builtin_nontemporal_store(outs[orow][ocol],
                                    &out[(size_t)(b0 + orow) * kT + t0 + ocol]);
    }
}

extern "C" void kernel_launch(void* const* d_in, const int* in_sizes, int n_in,
                              void* d_out, int out_size, void* d_ws, size_t ws_size,
                              hipStream_t stream) {
    const float* x           = (const float*)d_in[0];
    const int*   root_nodes  = (const int*)d_in[1];
    const float* root_biases = (const float*)d_in[2];
    const int*   nodes       = (const int*)d_in[3];
    const float* biases      = (const float*)d_in[4];
    const float* leaf_nodes  = (const float*)d_in[5];
    float*       out         = (float*)d_out;

    const size_t pack8_bytes = (size_t)(kLevels - 1) * kLvlPad * sizeof(int2); // 8 MiB
    const size_t fused_bytes = (size_t)kLvlPad * sizeof(int4);                 // 2 MiB
    const size_t pack9_bytes = (size_t)kLevels * kLvlPad * sizeof(int2);       // 9.44 MB
    dim3 grid(kB / kRows, kT / kTrees); // (2048, 4)

    if (ws_size >= pack8_bytes + fused_bytes) {
        int2* packed = (int2*)d_ws;
        int4* fused  = (int4*)((char*)d_ws + pack8_bytes);
        const int n = (kLevels - 1) * kLvlPad;
        pack_kernel<<<(n + 255) / 256, 256, 0, stream>>>(nodes, biases, packed, n);
        fuse_kernel<<<(kLvlPad + 255) / 256, 256, 0, stream>>>(nodes, biases,
                                                               leaf_nodes, fused);
        traverse_kernel<2><<<grid, kThreads, 0, stream>>>(
            x, root_nodes, root_biases, nodes, biases,
            packed, fused, leaf_nodes, out);
    } else if (ws_size >= pack9_bytes) {
        const int n = kLevels * kLvlPad;
        pack_kernel<<<(n + 255) / 256, 256, 0, stream>>>(nodes, biases, (int2*)d_ws, n);
        traverse_kernel<1><<<grid, kThreads, 0, stream>>>(
            x, root_nodes, root_biases, nodes, biases,
            (const int2*)d_ws, nullptr, leaf_nodes, out);
    } else {
        traverse_kernel<0><<<grid, kThreads, 0, stream>>>(
            x, root_nodes, root_biases, nodes, biases,
            nullptr, nullptr, leaf_nodes, out);
    }
}

// Round 7
// 71.507 us; speedup vs baseline: 2.2172x; 1.3957x over previous
//
#include <hip/hip_runtime.h>

// Problem constants (from the reference):
//   B=32768 batch, T=256 trees, D=10 depth, F=512 features, C=1 leaf dim
constexpr int kB = 32768;
constexpr int kT = 256;
constexpr int kD = 10;
constexpr int kF = 512;
constexpr int kLvlPad = kT << (kD - 1); // 131072
constexpr int kLevels = kD - 1;         // 9

constexpr int kRows    = 16;             // batch rows per block
constexpr int kTrees   = 64;             // trees per block (2 per thread)
constexpr int kThreads = 512;
constexpr int kXPad    = 516;            // padded x row stride (floats)

// Pair-table record counts / offsets (16B records in d_ws).
// Pair (i,i+1) table is indexed by the GLOBAL level-i index (width T*2^i):
//   {u32 n_top|nL<<9|nR<<18, f32 b_top, f32 bL, f32 bR}   (node idx < 512 = 9 bits)
// One dwordx4 gather advances TWO levels. Fused record (level 9 + leaf):
//   {n9, b9, leaf[2j], leaf[2j+1]} indexed by global level-9 index.
constexpr int kP1 = kT * 2;      // 512
constexpr int kP3 = kT * 8;      // 2048
constexpr int kP5 = kT * 32;     // 8192
constexpr int kP7 = kT * 128;    // 32768
constexpr int kFU = kT * 512;    // 131072
constexpr int kO1 = 0;
constexpr int kO3 = kO1 + kP1;   // 512
constexpr int kO5 = kO3 + kP3;   // 2560
constexpr int kO7 = kO5 + kP5;   // 10752
constexpr int kOF = kO7 + kP7;   // 43520
constexpr int kTotalRecs = kOF + kFU; // 174592
constexpr size_t kWsBytes = (size_t)kTotalRecs * 16; // 2,793,472 B

// Build all pair tables + fused table in one launch.
__global__ __launch_bounds__(256)
void prep_kernel(const int* __restrict__ nodes, const float* __restrict__ biases,
                 const float* __restrict__ leaf_nodes, int4* __restrict__ ws)
{
    int idx = blockIdx.x * 256 + threadIdx.x;
    if (idx < kOF) {
        int i, base;
        if      (idx < kO3) { i = 1; base = kO1; }
        else if (idx < kO5) { i = 3; base = kO3; }
        else if (idx < kO7) { i = 5; base = kO5; }
        else                { i = 7; base = kO7; }
        int j = idx - base;                      // global index into level i
        const int*   nt = nodes  + (size_t)(i - 1) * kLvlPad; // level i
        const float* bt = biases + (size_t)(i - 1) * kLvlPad;
        const int*   nc = nodes  + (size_t)i * kLvlPad;       // level i+1
        const float* bc = biases + (size_t)i * kLvlPad;
        unsigned int pk = (unsigned int)nt[j]
                        | ((unsigned int)nc[2 * j]     << 9)
                        | ((unsigned int)nc[2 * j + 1] << 18);
        ws[idx] = make_int4((int)pk, __float_as_int(bt[j]),
                            __float_as_int(bc[2 * j]),
                            __float_as_int(bc[2 * j + 1]));
    } else if (idx < kTotalRecs) {
        int j = idx - kOF;                       // global index into level 9
        const int   n9 = nodes [(size_t)(kD - 2) * kLvlPad + j];
        const float b9 = biases[(size_t)(kD - 2) * kLvlPad + j];
        ws[idx] = make_int4(n9, __float_as_int(b9),
                            __float_as_int(leaf_nodes[2 * j]),
                            __float_as_int(leaf_nodes[2 * j + 1]));
    }
}

// Block = 16 batch rows x 64 trees, 512 threads, 2 independent chains/thread.
// Wave lanes: lane&15 = row -> 16 lanes share each tree (shallow pair gathers
// coalesce within the tree's window). Chain: root -> 4 pair-steps -> fused =
// 6 dependent gathers instead of 11. Grid swizzled so the 4 tree-tile
// siblings of one x-tile occupy dispatch slots {k, k+8, k+16, k+24} -> same
// XCD, temporally adjacent -> x L2-resident across siblings.
__global__ __launch_bounds__(kThreads)
void traverse_pair_kernel(const float* __restrict__ x,
                          const int* __restrict__ root_nodes,
                          const float* __restrict__ root_biases,
                          const int4* __restrict__ ws,
                          float* __restrict__ out)
{
    __shared__ float xs[kRows][kXPad];        // 33,024 B
    __shared__ float outs[kRows][kTrees + 1]; //  4,160 B

    const int bid = blockIdx.x;
    const int w   = bid >> 5;        // 32-block window
    const int s   = bid & 31;
    const int bx  = w * 8 + (s & 7); // x-tile, [0, 2048)
    const int by  = s >> 3;          // tree tile, [0, 4)
    const int b0  = bx * kRows;
    const int t0  = by * kTrees;
    const int tid = threadIdx.x;

    // Stage 16 x rows (2048 float4), coalesced.
    {
        const float4* xg = reinterpret_cast<const float4*>(x + (size_t)b0 * kF);
#pragma unroll
        for (int k = 0; k < 4; ++k) {
            int j = tid + k * kThreads;   // 0..2047
            int r = j >> 7;
            int c = j & 127;
            float4 v = xg[(size_t)r * (kF / 4) + c];
            *reinterpret_cast<float4*>(&xs[r][c * 4]) = v;
        }
    }
    __syncthreads();

    const int r  = tid & (kRows - 1); // row within tile
    const int tt = tid >> 4;          // 0..31
    const int tA = t0 + tt;
    const int tB = t0 + tt + 32;
    const float* __restrict__ xrow = xs[r];

    // Root (tree uniform across each 16-lane group -> broadcast loads).
    int pA = 2 * tA + (xrow[root_nodes[tA]] <= root_biases[tA] ? 1 : 0);
    int pB = 2 * tB + (xrow[root_nodes[tB]] <= root_biases[tB] ? 1 : 0);

    const int4* __restrict__ P1 = ws + kO1;
    const int4* __restrict__ P3 = ws + kO3;
    const int4* __restrict__ P5 = ws + kO5;
    const int4* __restrict__ P7 = ws + kO7;
    const int4* __restrict__ FU = ws + kOF;

#define PAIR_STEP(TBL)                                                        \
    {                                                                         \
        int4 ra = TBL[pA];                                                    \
        int4 rb = TBL[pB];                                                    \
        unsigned int na = (unsigned int)ra.x, nb = (unsigned int)rb.x;        \
        int c0a = xrow[na & 511u] <= __int_as_float(ra.y) ? 1 : 0;            \
        int c0b = xrow[nb & 511u] <= __int_as_float(rb.y) ? 1 : 0;            \
        int nca = c0a ? (int)((na >> 18) & 511u) : (int)((na >> 9) & 511u);   \
        int ncb = c0b ? (int)((nb >> 18) & 511u) : (int)((nb >> 9) & 511u);   \
        int bba = c0a ? ra.w : ra.z;                                          \
        int bbb = c0b ? rb.w : rb.z;                                          \
        int c1a = xrow[nca] <= __int_as_float(bba) ? 1 : 0;                   \
        int c1b = xrow[ncb] <= __int_as_float(bbb) ? 1 : 0;                   \
        pA = 4 * pA + 2 * c0a + c1a;                                          \
        pB = 4 * pB + 2 * c0b + c1b;                                          \
    }

    PAIR_STEP(P1)   // levels 1,2
    PAIR_STEP(P3)   // levels 3,4
    PAIR_STEP(P5)   // levels 5,6
    PAIR_STEP(P7)   // levels 7,8
#undef PAIR_STEP

    // Fused level 9 + leaf: one 16B gather finishes each tree.
    {
        int4 fA = FU[pA];
        int4 fB = FU[pB];
        outs[r][tt] =
            __int_as_float(xrow[fA.x] <= __int_as_float(fA.y) ? fA.w : fA.z);
        outs[r][tt + 32] =
            __int_as_float(xrow[fB.x] <= __int_as_float(fB.y) ? fB.w : fB.z);
    }
    __syncthreads();

#pragma unroll
    for (int k = 0; k < 2; ++k) {
        int j    = tid + k * kThreads;  // 0..1023
        int orow = j >> 6;              // 0..15
        int ocol = j & 63;              // 0..63
        __builtin_nontemporal_store(outs[orow][ocol],
                                    &out[(size_t)(b0 + orow) * kT + t0 + ocol]);
    }
}

// Fallback (no workspace): straightforward per-level walk (round-5 layout).
__global__ __launch_bounds__(kThreads)
void traverse_plain_kernel(const float* __restrict__ x,
                           const int* __restrict__ root_nodes,
                           const float* __restrict__ root_biases,
                           const int* __restrict__ nodes,
                           const float* __restrict__ biases,
                           const float* __restrict__ leaf_nodes,
                           float* __restrict__ out)
{
    __shared__ float xs[kRows][kXPad];
    __shared__ float outs[kRows][kTrees + 1];

    const int b0  = blockIdx.x * kRows;
    const int t0  = blockIdx.y * kTrees;
    const int tid = threadIdx.x;

    {
        const float4* xg = reinterpret_cast<const float4*>(x + (size_t)b0 * kF);
#pragma unroll
        for (int k = 0; k < 4; ++k) {
            int j = tid + k * kThreads;
            int r = j >> 7;
            int c = j & 127;
            float4 v = xg[(size_t)r * (kF / 4) + c];
            *reinterpret_cast<float4*>(&xs[r][c * 4]) = v;
        }
    }
    __syncthreads();

    const int r  = tid & (kRows - 1);
    const int tt = tid >> 4;
    const int tA = t0 + tt;
    const int tB = t0 + tt + 32;
    const float* __restrict__ xrow = xs[r];

    int pA = 2 * tA + (xrow[root_nodes[tA]] <= root_biases[tA] ? 1 : 0);
    int pB = 2 * tB + (xrow[root_nodes[tB]] <= root_biases[tB] ? 1 : 0);

#pragma unroll
    for (int i = 1; i < kD; ++i) {
        const int*   ln = nodes  + (size_t)(i - 1) * kLvlPad;
        const float* lb = biases + (size_t)(i - 1) * kLvlPad;
        int   nA = ln[pA], nB = ln[pB];
        float bA = lb[pA], bB = lb[pB];
        pA = 2 * pA + (xrow[nA] <= bA ? 1 : 0);
        pB = 2 * pB + (xrow[nB] <= bB ? 1 : 0);
    }

    outs[r][tt]      = leaf_nodes[pA];
    outs[r][tt + 32] = leaf_nodes[pB];
    __syncthreads();

#pragma unroll
    for (int k = 0; k < 2; ++k) {
        int j    = tid + k * kThreads;
        int orow = j >> 6;
        int ocol = j & 63;
        __builtin_nontemporal_store(outs[orow][ocol],
                                    &out[(size_t)(b0 + orow) * kT + t0 + ocol]);
    }
}

extern "C" void kernel_launch(void* const* d_in, const int* in_sizes, int n_in,
                              void* d_out, int out_size, void* d_ws, size_t ws_size,
                              hipStream_t stream) {
    const float* x           = (const float*)d_in[0];
    const int*   root_nodes  = (const int*)d_in[1];
    const float* root_biases = (const float*)d_in[2];
    const int*   nodes       = (const int*)d_in[3];
    const float* biases      = (const float*)d_in[4];
    const float* leaf_nodes  = (const float*)d_in[5];
    float*       out         = (float*)d_out;

    if (ws_size >= kWsBytes) {
        prep_kernel<<<(kTotalRecs + 255) / 256, 256, 0, stream>>>(
            nodes, biases, leaf_nodes, (int4*)d_ws);
        const int nblocks = (kB / kRows) * (kT / kTrees); // 8192
        traverse_pair_kernel<<<nblocks, kThreads, 0, stream>>>(
            x, root_nodes, root_biases, (const int4*)d_ws, out);
    } else {
        dim3 grid(kB / kRows, kT / kTrees); // (2048, 4)
        traverse_plain_kernel<<<grid, kThreads, 0, stream>>>(
            x, root_nodes, root_biases, nodes, biases, leaf_nodes, out);
    }
}

// Round 8
// 67.359 us; speedup vs baseline: 2.3538x; 1.0616x over previous
//
#include <hip/hip_runtime.h>

// Problem constants (from the reference):
//   B=32768 batch, T=256 trees, D=10 depth, F=512 features, C=1 leaf dim
constexpr int kB = 32768;
constexpr int kT = 256;
constexpr int kD = 10;
constexpr int kF = 512;
constexpr int kLvlPad = kT << (kD - 1); // 131072
constexpr int kLevels = kD - 1;         // 9

constexpr int kRows    = 16;             // batch rows per block
constexpr int kTrees   = 128;            // trees per block (4 chains per thread)
constexpr int kChains  = 4;
constexpr int kThreads = 512;
constexpr int kXPad    = 516;            // padded x row stride (floats)
constexpr int kOPad    = kTrees + 1;     // outs stride 129 -> bank (r+tt)%32

// Pair-table record counts / offsets (16B records in d_ws).
// Pair (i,i+1) table indexed by the GLOBAL level-i index (width T*2^i):
//   {u32 n_top|nL<<9|nR<<18, f32 b_top, f32 bL, f32 bR}  (node idx < 512)
// One dwordx4 gather advances TWO levels. Fused record (level 9 + leaf):
//   {n9, b9, leaf[2j], leaf[2j+1]} indexed by global level-9 index.
constexpr int kP1 = kT * 2;      // 512
constexpr int kP3 = kT * 8;      // 2048
constexpr int kP5 = kT * 32;     // 8192
constexpr int kP7 = kT * 128;    // 32768
constexpr int kFU = kT * 512;    // 131072
constexpr int kO1 = 0;
constexpr int kO3 = kO1 + kP1;   // 512
constexpr int kO5 = kO3 + kP3;   // 2560
constexpr int kO7 = kO5 + kP5;   // 10752
constexpr int kOF = kO7 + kP7;   // 43520
constexpr int kTotalRecs = kOF + kFU; // 174592
constexpr size_t kWsBytes = (size_t)kTotalRecs * 16; // 2,793,472 B

// Build all pair tables + fused table in one launch.
__global__ __launch_bounds__(256)
void prep_kernel(const int* __restrict__ nodes, const float* __restrict__ biases,
                 const float* __restrict__ leaf_nodes, int4* __restrict__ ws)
{
    int idx = blockIdx.x * 256 + threadIdx.x;
    if (idx < kOF) {
        int i, base;
        if      (idx < kO3) { i = 1; base = kO1; }
        else if (idx < kO5) { i = 3; base = kO3; }
        else if (idx < kO7) { i = 5; base = kO5; }
        else                { i = 7; base = kO7; }
        int j = idx - base;                      // global index into level i
        const int*   nt = nodes  + (size_t)(i - 1) * kLvlPad; // level i
        const float* bt = biases + (size_t)(i - 1) * kLvlPad;
        const int*   nc = nodes  + (size_t)i * kLvlPad;       // level i+1
        const float* bc = biases + (size_t)i * kLvlPad;
        unsigned int pk = (unsigned int)nt[j]
                        | ((unsigned int)nc[2 * j]     << 9)
                        | ((unsigned int)nc[2 * j + 1] << 18);
        ws[idx] = make_int4((int)pk, __float_as_int(bt[j]),
                            __float_as_int(bc[2 * j]),
                            __float_as_int(bc[2 * j + 1]));
    } else if (idx < kTotalRecs) {
        int j = idx - kOF;                       // global index into level 9
        const int   n9 = nodes [(size_t)(kD - 2) * kLvlPad + j];
        const float b9 = biases[(size_t)(kD - 2) * kLvlPad + j];
        ws[idx] = make_int4(n9, __float_as_int(b9),
                            __float_as_int(leaf_nodes[2 * j]),
                            __float_as_int(leaf_nodes[2 * j + 1]));
    }
}

// Block = 16 batch rows x 128 trees, 512 threads, 4 independent chains per
// thread (trees tt+32k) -> 4 gathers in flight per dependent step. Wave
// lanes: lane&15 = row -> 16 lanes share each tree so shallow pair gathers
// coalesce within the tree's window. Chain: root -> 4 pair-steps -> fused =
// 6 dependent gathers. xs buffer is reused as the output staging buffer
// after the last xrow read (keeps LDS at 33KB -> 4 blocks/CU). Grid
// swizzled so the 2 tree-tile siblings of an x-tile sit 8 dispatch slots
// apart (same XCD) -> x L2-resident across siblings.
__global__ __launch_bounds__(kThreads)
void traverse_pair_kernel(const float* __restrict__ x,
                          const int* __restrict__ root_nodes,
                          const float* __restrict__ root_biases,
                          const int4* __restrict__ ws,
                          float* __restrict__ out)
{
    __shared__ float xs[kRows][kXPad];        // 33,024 B (reused for outs)
    float* outs = &xs[0][0];                  // alias: [kRows][kOPad]

    const int bid = blockIdx.x;
    const int w   = bid >> 4;        // 16-block window
    const int s   = bid & 15;
    const int bx  = w * 8 + (s & 7); // x-tile, [0, 2048)
    const int by  = s >> 3;          // tree tile, [0, 2)
    const int b0  = bx * kRows;
    const int t0  = by * kTrees;
    const int tid = threadIdx.x;

    // Stage 16 x rows (2048 float4), coalesced.
    {
        const float4* xg = reinterpret_cast<const float4*>(x + (size_t)b0 * kF);
#pragma unroll
        for (int k = 0; k < 4; ++k) {
            int j = tid + k * kThreads;   // 0..2047
            int r = j >> 7;
            int c = j & 127;
            float4 v = xg[(size_t)r * (kF / 4) + c];
            *reinterpret_cast<float4*>(&xs[r][c * 4]) = v;
        }
    }
    __syncthreads();

    const int r  = tid & (kRows - 1); // row within tile
    const int tt = tid >> 4;          // 0..31
    const float* __restrict__ xrow = xs[r];

    int p[kChains];
#pragma unroll
    for (int c = 0; c < kChains; ++c) {
        int t = t0 + tt + 32 * c;
        p[c] = 2 * t + (xrow[root_nodes[t]] <= root_biases[t] ? 1 : 0);
    }

    const int4* __restrict__ P1 = ws + kO1;
    const int4* __restrict__ P3 = ws + kO3;
    const int4* __restrict__ P5 = ws + kO5;
    const int4* __restrict__ P7 = ws + kO7;
    const int4* __restrict__ FU = ws + kOF;

#define PAIR_STEP(TBL)                                                        \
    {                                                                         \
        int4 rec[kChains];                                                    \
        _Pragma("unroll")                                                     \
        for (int c = 0; c < kChains; ++c) rec[c] = TBL[p[c]];                 \
        _Pragma("unroll")                                                     \
        for (int c = 0; c < kChains; ++c) {                                   \
            unsigned int n = (unsigned int)rec[c].x;                          \
            int c0 = xrow[n & 511u] <= __int_as_float(rec[c].y) ? 1 : 0;      \
            int nc = c0 ? (int)((n >> 18) & 511u) : (int)((n >> 9) & 511u);   \
            int bb = c0 ? rec[c].w : rec[c].z;                                \
            int c1 = xrow[nc] <= __int_as_float(bb) ? 1 : 0;                  \
            p[c] = 4 * p[c] + 2 * c0 + c1;                                    \
        }                                                                     \
    }

    PAIR_STEP(P1)   // levels 1,2
    PAIR_STEP(P3)   // levels 3,4
    PAIR_STEP(P5)   // levels 5,6
    PAIR_STEP(P7)   // levels 7,8
#undef PAIR_STEP

    // Fused level 9 + leaf: one 16B gather finishes each tree.
    float leaf[kChains];
    {
        int4 rec[kChains];
#pragma unroll
        for (int c = 0; c < kChains; ++c) rec[c] = FU[p[c]];
#pragma unroll
        for (int c = 0; c < kChains; ++c) {
            leaf[c] = __int_as_float(
                xrow[rec[c].x] <= __int_as_float(rec[c].y) ? rec[c].w
                                                           : rec[c].z);
        }
    }

    // xs is dead now; reuse it as the output staging buffer.
    __syncthreads();
#pragma unroll
    for (int c = 0; c < kChains; ++c)
        outs[r * kOPad + tt + 32 * c] = leaf[c];
    __syncthreads();

#pragma unroll
    for (int k = 0; k < 4; ++k) {
        int j    = tid + k * kThreads;  // 0..2047
        int orow = j >> 7;              // 0..15
        int ocol = j & 127;             // 0..127
        __builtin_nontemporal_store(outs[orow * kOPad + ocol],
                                    &out[(size_t)(b0 + orow) * kT + t0 + ocol]);
    }
}

// Fallback (no workspace): straightforward per-level walk (round-5 layout).
__global__ __launch_bounds__(kThreads)
void traverse_plain_kernel(const float* __restrict__ x,
                           const int* __restrict__ root_nodes,
                           const float* __restrict__ root_biases,
                           const int* __restrict__ nodes,
                           const float* __restrict__ biases,
                           const float* __restrict__ leaf_nodes,
                           float* __restrict__ out)
{
    __shared__ float xs[kRows][kXPad];
    __shared__ float outs[kRows][65];

    const int b0  = blockIdx.x * kRows;
    const int t0  = blockIdx.y * 64;
    const int tid = threadIdx.x;

    {
        const float4* xg = reinterpret_cast<const float4*>(x + (size_t)b0 * kF);
#pragma unroll
        for (int k = 0; k < 4; ++k) {
            int j = tid + k * kThreads;
            int r = j >> 7;
            int c = j & 127;
            float4 v = xg[(size_t)r * (kF / 4) + c];
            *reinterpret_cast<float4*>(&xs[r][c * 4]) = v;
        }
    }
    __syncthreads();

    const int r  = tid & (kRows - 1);
    const int tt = tid >> 4;
    const int tA = t0 + tt;
    const int tB = t0 + tt + 32;
    const float* __restrict__ xrow = xs[r];

    int pA = 2 * tA + (xrow[root_nodes[tA]] <= root_biases[tA] ? 1 : 0);
    int pB = 2 * tB + (xrow[root_nodes[tB]] <= root_biases[tB] ? 1 : 0);

#pragma unroll
    for (int i = 1; i < kD; ++i) {
        const int*   ln = nodes  + (size_t)(i - 1) * kLvlPad;
        const float* lb = biases + (size_t)(i - 1) * kLvlPad;
        int   nA = ln[pA], nB = ln[pB];
        float bA = lb[pA], bB = lb[pB];
        pA = 2 * pA + (xrow[nA] <= bA ? 1 : 0);
        pB = 2 * pB + (xrow[nB] <= bB ? 1 : 0);
    }

    outs[r][tt]      = leaf_nodes[pA];
    outs[r][tt + 32] = leaf_nodes[pB];
    __syncthreads();

#pragma unroll
    for (int k = 0; k < 2; ++k) {
        int j    = tid + k * kThreads;
        int orow = j >> 6;
        int ocol = j & 63;
        __builtin_nontemporal_store(outs[orow][ocol],
                                    &out[(size_t)(b0 + orow) * kT + t0 + ocol]);
    }
}

extern "C" void kernel_launch(void* const* d_in, const int* in_sizes, int n_in,
                              void* d_out, int out_size, void* d_ws, size_t ws_size,
                              hipStream_t stream) {
    const float* x           = (const float*)d_in[0];
    const int*   root_nodes  = (const int*)d_in[1];
    const float* root_biases = (const float*)d_in[2];
    const int*   nodes       = (const int*)d_in[3];
    const float* biases      = (const float*)d_in[4];
    const float* leaf_nodes  = (const float*)d_in[5];
    float*       out         = (float*)d_out;

    if (ws_size >= kWsBytes) {
        prep_kernel<<<(kTotalRecs + 255) / 256, 256, 0, stream>>>(
            nodes, biases, leaf_nodes, (int4*)d_ws);
        const int nblocks = (kB / kRows) * (kT / kTrees); // 4096
        traverse_pair_kernel<<<nblocks, kThreads, 0, stream>>>(
            x, root_nodes, root_biases, (const int4*)d_ws, out);
    } else {
        dim3 grid(kB / kRows, kT / 64); // (2048, 4)
        traverse_plain_kernel<<<grid, kThreads, 0, stream>>>(
            x, root_nodes, root_biases, nodes, biases, leaf_nodes, out);
    }
}